// Round 2
// 378.957 us; speedup vs baseline: 1.1198x; 1.1198x over previous
//
#include <hip/hip_runtime.h>
#include <hip/hip_bf16.h>

#define IN_SIZE 4096
#define OUT_SIZE 4096
#define BATCH 4096

// packed-bin parameters: 512 blocks x 8192 entries; 1024 cells of 4 W-rows.
// Bins are exact (histogram + scan + sorted emit) — no padding, no overflow.
#define NBLK 512
#define CHUNK 8192
#define NCELL 1024

typedef __bf16 bf16x8 __attribute__((ext_vector_type(8)));
typedef float f32x4 __attribute__((ext_vector_type(4)));

// ------------------------------------------------ Phase A: packed sorted bins
__global__ __launch_bounds__(256) void bin_kernel(const float* __restrict__ vals,
                                                  const int* __restrict__ iin,
                                                  const int* __restrict__ iout,
                                                  uint2* __restrict__ bkt,
                                                  int* __restrict__ off, int nnz) {
    __shared__ int hist[NCELL];
    __shared__ int pref[NCELL + 1];
    __shared__ int partial[256];
    __shared__ unsigned short sidx[CHUNK];   // 16 KB
    const int b = blockIdx.x, tid = threadIdx.x;
    const int base = b * CHUNK;

    for (int c = tid; c < NCELL; c += 256) hist[c] = 0;
    __syncthreads();
    for (int i = tid; i < CHUNK; i += 256) {
        const int k = base + i;
        if (k < nnz) atomicAdd(&hist[iout[k] >> 2], 1);
    }
    __syncthreads();

    const int h0 = hist[4 * tid], h1 = hist[4 * tid + 1];
    const int h2 = hist[4 * tid + 2], h3 = hist[4 * tid + 3];
    const int mysum = h0 + h1 + h2 + h3;
    partial[tid] = mysum;
    __syncthreads();
    for (int d = 1; d < 256; d <<= 1) {
        const int v = (tid >= d) ? partial[tid - d] : 0;
        __syncthreads();
        partial[tid] += v;
        __syncthreads();
    }
    const int excl = partial[tid] - mysum;
    pref[4 * tid]     = excl;
    pref[4 * tid + 1] = excl + h0;
    pref[4 * tid + 2] = excl + h0 + h1;
    pref[4 * tid + 3] = excl + h0 + h1 + h2;
    if (tid == 255) pref[NCELL] = partial[255];
    __syncthreads();

    for (int c = tid; c < NCELL; c += 256) hist[c] = 0;
    __syncthreads();
    for (int i = tid; i < CHUNK; i += 256) {
        const int k = base + i;
        if (k < nnz) {
            const int c = iout[k] >> 2;
            const int pos = atomicAdd(&hist[c], 1);
            sidx[pref[c] + pos] = (unsigned short)i;
        }
    }
    for (int c = tid; c < NCELL + 1; c += 256) off[b * (NCELL + 1) + c] = pref[c];
    __syncthreads();

    const int total = pref[NCELL];
    for (int s = tid; s < total; s += 256) {
        const int k = base + sidx[s];
        uint2 e;
        e.x = __builtin_bit_cast(unsigned, vals[k]);
        e.y = (unsigned)(((iout[k] & 3) << 12) | iin[k]);
        bkt[(size_t)base + s] = e;
    }
}

// ---------------- Phase B: per-cell LDS fp32 accumulate -> bf16 W (+ x cvt)
__global__ __launch_bounds__(256) void accum_kernel(const uint2* __restrict__ bkt,
                                                    const int* __restrict__ off,
                                                    __bf16* __restrict__ W,
                                                    const f32x4* __restrict__ xin,
                                                    bf16x8* __restrict__ xout) {
    __shared__ float acc[4 * 4096];     // 64 KB
    __shared__ int loff[NBLK];
    __shared__ int lpref[NBLK + 1];
    __shared__ int partial[256];
    const int cell = blockIdx.x, tid = threadIdx.x;

    for (int t = tid; t < 4 * 4096; t += 256) acc[t] = 0.f;
    for (int b = tid; b < NBLK; b += 256) {
        const int o0 = off[b * (NCELL + 1) + cell];
        const int o1 = off[b * (NCELL + 1) + cell + 1];
        loff[b] = o0;
        lpref[b] = o1 - o0;
    }
    __syncthreads();

    const int c0 = lpref[2 * tid], c1 = lpref[2 * tid + 1];
    const int mysum = c0 + c1;
    partial[tid] = mysum;
    __syncthreads();
    for (int d = 1; d < 256; d <<= 1) {
        const int v = (tid >= d) ? partial[tid - d] : 0;
        __syncthreads();
        partial[tid] += v;
        __syncthreads();
    }
    const int excl = partial[tid] - mysum;
    lpref[2 * tid]     = excl;
    lpref[2 * tid + 1] = excl + c0;
    if (tid == 255) lpref[NBLK] = partial[255];
    __syncthreads();

    const int total = lpref[NBLK];
    for (int s = tid; s < total; s += 256) {
        int lo = 0, hi = NBLK;
        while (hi - lo > 1) {
            const int mid = (lo + hi) >> 1;
            if (lpref[mid] <= s) lo = mid; else hi = mid;
        }
        const uint2 e = bkt[(size_t)lo * CHUNK + loff[lo] + (s - lpref[lo])];
        atomicAdd(&acc[((e.y >> 12) & 3u) * 4096 + (e.y & 0xFFFu)],
                  __builtin_bit_cast(float, e.x));
    }
    __syncthreads();

    bf16x8* out = (bf16x8*)(W + (size_t)cell * 4 * 4096);
    for (int t = tid; t < 2048; t += 256) {
        bf16x8 o;
#pragma unroll
        for (int j = 0; j < 8; ++j) o[j] = (__bf16)acc[t * 8 + j];
        out[t] = o;
    }

    const int xbase = blockIdx.x * 2048;
    for (int t = tid; t < 2048; t += 256) {
        const int idx = xbase + t;
        const f32x4 a = xin[2 * idx];
        const f32x4 bq = xin[2 * idx + 1];
        bf16x8 o;
        o[0] = (__bf16)a[0];  o[1] = (__bf16)a[1];  o[2] = (__bf16)a[2];  o[3] = (__bf16)a[3];
        o[4] = (__bf16)bq[0]; o[5] = (__bf16)bq[1]; o[6] = (__bf16)bq[2]; o[7] = (__bf16)bq[3];
        xout[idx] = o;
    }
}

// ----------------------------------------------------------------- GEMM
// C[M][N] = A[M][K] * B[N][K]^T, all 4096, A/B bf16 row-major, C fp32.
// 256x256 tile, BK=32, 8 waves (2M x 4N), 8x4 16x16x32-bf16 frags/wave.
// 4-deep LDS pipeline (4 x 32 KB = 128 KB), counted vmcnt(8) per K-tile
// (loads for tiles t+2,t+3 stay in flight across barriers), raw s_barrier,
// setprio(1) around MFMA clusters, bijective XCD blockIdx swizzle.
// XOR swizzle at 16B-chunk granularity (slot = q ^ ((row>>1)&3)), applied
// on the pre-swizzled GLOBAL source (global_load_lds dest must be linear).
#define GNT 128   // 4096 / BK(=32)

#define STAGE_A(T)                                                            \
  do {                                                                        \
    const __bf16* s_ = gA0 + (size_t)(T) * 32;                                \
    __bf16* d_ = &smem[((T) & 3) * 16384 + tid * 8];                          \
    __builtin_amdgcn_global_load_lds(                                         \
        (const __attribute__((address_space(1))) void*)s_,                    \
        (__attribute__((address_space(3))) void*)d_, 16, 0, 0);               \
    __builtin_amdgcn_global_load_lds(                                         \
        (const __attribute__((address_space(1))) void*)(s_ + (size_t)524288), \
        (__attribute__((address_space(3))) void*)(d_ + 4096), 16, 0, 0);      \
  } while (0)

#define STAGE_B(T)                                                            \
  do {                                                                        \
    const __bf16* s_ = gB0 + (size_t)(T) * 32;                                \
    __bf16* d_ = &smem[((T) & 3) * 16384 + 8192 + tid * 8];                   \
    __builtin_amdgcn_global_load_lds(                                         \
        (const __attribute__((address_space(1))) void*)s_,                    \
        (__attribute__((address_space(3))) void*)d_, 16, 0, 0);               \
    __builtin_amdgcn_global_load_lds(                                         \
        (const __attribute__((address_space(1))) void*)(s_ + (size_t)524288), \
        (__attribute__((address_space(3))) void*)(d_ + 4096), 16, 0, 0);      \
  } while (0)

#define VMW8 asm volatile("s_waitcnt vmcnt(8)" ::: "memory")
#define VMW4 asm volatile("s_waitcnt vmcnt(4)" ::: "memory")
#define VMW0 asm volatile("s_waitcnt vmcnt(0)" ::: "memory")
#define VMWN ((void)0)

#define GTILE(T, DOSTAGE, VMWAIT, ENDBAR)                                     \
  do {                                                                        \
    const __bf16* bp_ = &smem[((T) & 3) * 16384];                             \
    bf16x8 bfr_[4], af_[4];                                                   \
    _Pragma("unroll") for (int j_ = 0; j_ < 4; ++j_)                          \
        bfr_[j_] = *(const bf16x8*)(bp_ + offB[j_]);                          \
    _Pragma("unroll") for (int i_ = 0; i_ < 4; ++i_)                          \
        af_[i_] = *(const bf16x8*)(bp_ + offA[i_]);                           \
    if (DOSTAGE) STAGE_A((T) + 3);                                            \
    __builtin_amdgcn_s_barrier();                                             \
    __builtin_amdgcn_s_setprio(1);                                            \
    _Pragma("unroll") for (int i_ = 0; i_ < 4; ++i_)                          \
        _Pragma("unroll") for (int j_ = 0; j_ < 4; ++j_)                      \
            acc[i_][j_] = __builtin_amdgcn_mfma_f32_16x16x32_bf16(            \
                af_[i_], bfr_[j_], acc[i_][j_], 0, 0, 0);                     \
    __builtin_amdgcn_s_setprio(0);                                            \
    __builtin_amdgcn_s_barrier();                                             \
    _Pragma("unroll") for (int i_ = 0; i_ < 4; ++i_)                          \
        af_[i_] = *(const bf16x8*)(bp_ + offA[4 + i_]);                       \
    if (DOSTAGE) STAGE_B((T) + 3);                                            \
    __builtin_amdgcn_s_barrier();                                             \
    __builtin_amdgcn_s_setprio(1);                                            \
    _Pragma("unroll") for (int i_ = 0; i_ < 4; ++i_)                          \
        _Pragma("unroll") for (int j_ = 0; j_ < 4; ++j_)                      \
            acc[4 + i_][j_] = __builtin_amdgcn_mfma_f32_16x16x32_bf16(        \
                af_[i_], bfr_[j_], acc[4 + i_][j_], 0, 0, 0);                 \
    __builtin_amdgcn_s_setprio(0);                                            \
    asm volatile("s_waitcnt lgkmcnt(0)" ::: "memory");                        \
    VMWAIT;                                                                   \
    if (ENDBAR) __builtin_amdgcn_s_barrier();                                 \
  } while (0)

__global__ __launch_bounds__(512, 2) void gemm_bt_kernel(
    const __bf16* __restrict__ A,
    const __bf16* __restrict__ B,
    float* __restrict__ C) {
    __shared__ __bf16 smem[4 * 16384];   // 128 KB: 4 bufs x (A 8192 | B 8192)

    const int tid   = threadIdx.x;
    const int lane  = tid & 63;
    const int wv    = tid >> 6;
    const int wm    = wv >> 2;           // 0..1  -> 128 M-rows each
    const int wn    = wv & 3;            // 0..3  -> 64 N-cols each
    const int row16 = lane & 15;
    const int quad  = lane >> 4;

    // bijective XCD swizzle: 256 blocks, 8 XCDs, 32 contiguous tiles/XCD
    const int swz = (blockIdx.x & 7) * 32 + (blockIdx.x >> 3);
    const int bm  = (swz >> 4) * 256;
    const int bn  = (swz & 15) * 256;

    // staging: 512 thr x 16B = 8 KB = 128 rows of 64 B; 2 issues per matrix.
    // slot p holds pre-swizzle chunk q = p ^ ((row>>1)&3)  (inverse == itself)
    const int sr = tid >> 2;                       // local row 0..127
    const int sq = (tid & 3) ^ ((sr >> 1) & 3);    // source 16B-chunk
    const __bf16* gA0 = A + (size_t)(bm + sr) * 4096 + sq * 8;
    const __bf16* gB0 = B + (size_t)(bn + sr) * 4096 + sq * 8;

    // ds_read element offsets (per-lane, constant across tiles)
    int offA[8], offB[4];
#pragma unroll
    for (int i = 0; i < 8; ++i) {
        const int ra = wm * 128 + i * 16 + row16;
        offA[i] = ra * 32 + ((quad ^ ((ra >> 1) & 3)) * 8);
    }
#pragma unroll
    for (int j = 0; j < 4; ++j) {
        const int rb = wn * 64 + j * 16 + row16;
        offB[j] = 8192 + rb * 32 + ((quad ^ ((rb >> 1) & 3)) * 8);
    }

    f32x4 acc[8][4] = {};

    // prologue: tiles 0..2 in flight (12 loads), land tile 0
    STAGE_A(0); STAGE_B(0);
    STAGE_A(1); STAGE_B(1);
    STAGE_A(2); STAGE_B(2);
    VMW8;
    __builtin_amdgcn_s_barrier();

    int t = 0;
    for (; t < GNT - 3; ++t) GTILE(t, true, VMW8, true);
    GTILE(t, false, VMW4, true); ++t;
    GTILE(t, false, VMW0, true); ++t;
    GTILE(t, false, VMWN, false);

#pragma unroll
    for (int i = 0; i < 8; ++i) {
        const int rbase = bm + wm * 128 + i * 16 + quad * 4;
#pragma unroll
        for (int j = 0; j < 4; ++j) {
            const int col = bn + wn * 64 + j * 16 + row16;
#pragma unroll
            for (int r = 0; r < 4; ++r)
                C[(size_t)(rbase + r) * 4096 + col] = acc[i][j][r];
        }
    }
}

extern "C" void kernel_launch(void* const* d_in, const int* in_sizes, int n_in,
                              void* d_out, int out_size, void* d_ws, size_t ws_size,
                              hipStream_t stream) {
    const float* x    = (const float*)d_in[0];
    const float* vals = (const float*)d_in[1];
    const int*   iin  = (const int*)d_in[2];
    const int*   iout = (const int*)d_in[3];
    float*       C    = (float*)d_out;
    const int    nnz  = in_sizes[1];

    // workspace: Wb 32MB | Xb 32MB | bkt 32MB (packed) | off 2.1MB  = 98.1 MB
    char*   ws  = (char*)d_ws;
    __bf16* Wb  = (__bf16*)ws;
    __bf16* Xb  = (__bf16*)(ws + ((size_t)32 << 20));
    uint2*  bkt = (uint2*)(ws + ((size_t)64 << 20));
    int*    off = (int*)(ws + ((size_t)96 << 20));

    bin_kernel<<<NBLK, 256, 0, stream>>>(vals, iin, iout, bkt, off, nnz);
    accum_kernel<<<NCELL, 256, 0, stream>>>(bkt, off, Wb, (const f32x4*)x, (bf16x8*)Xb);
    gemm_bt_kernel<<<256, 512, 0, stream>>>(Xb, Wb, C);
}